// Round 1
// baseline (90.455 us; speedup 1.0000x reference)
//
#include <hip/hip_runtime.h>

// KAN 1D spline: out = phi(t) + beta*x + bias, t = clamp((x-shift)*scale, -1.5, 1.5)
// phi = sum_k alpha[c,k] * max(1 - |(t - c_k)/delta|, 0), centers = linspace(-1,1,16)
// Hat basis => at most 2 adjacent taps nonzero => 2-tap interpolation.
//
// B=8, C=64, H=128, W=128, K=16. Memory-bound: 32MiB in + 32MiB out.

constexpr int Bc = 8, Cc = 64, Hc = 128, Wc = 128, Kc = 16;
constexpr int HW = Hc * Wc;                 // 16384 elements per (b,c) plane
constexpr int ELEMS_PER_BLOCK = 4096;       // quarter plane -> channel uniform per block
constexpr int THREADS = 256;
constexpr int F4_PER_THREAD = ELEMS_PER_BLOCK / 4 / THREADS;  // 4

__global__ __launch_bounds__(THREADS)
void kan_spline_kernel(const float* __restrict__ x,
                       const float* __restrict__ alpha,
                       const float* __restrict__ beta,
                       const float* __restrict__ bias,
                       const float* __restrict__ shift,
                       const float* __restrict__ scale,
                       float* __restrict__ out)
{
    __shared__ float sA[Kc];

    const int blk = blockIdx.x;
    // 4 blocks per plane; plane index = b*Cc + c  ->  c = (blk/4) % 64
    const int c = (blk >> 2) & (Cc - 1);

    if (threadIdx.x < Kc) sA[threadIdx.x] = alpha[c * Kc + threadIdx.x];
    const float sh = shift[c];
    const float sc = scale[c];
    const float be = beta[c];
    const float bi = bias[c];
    __syncthreads();

    const int base = blk * ELEMS_PER_BLOCK;
    const float4* __restrict__ x4 = reinterpret_cast<const float4*>(x + base);
    float4*       __restrict__ o4 = reinterpret_cast<float4*>(out + base);

    #pragma unroll
    for (int it = 0; it < F4_PER_THREAD; ++it) {
        const int idx = it * THREADS + threadIdx.x;
        float4 v = x4[idx];
        float r[4] = {v.x, v.y, v.z, v.w};
        float o[4];
        #pragma unroll
        for (int j = 0; j < 4; ++j) {
            const float xx = r[j];
            float t = (xx - sh) * sc;
            t = fminf(fmaxf(t, -1.5f), 1.5f);
            // p in [-3.75, 18.75]; delta = 2/15, 1/delta = 7.5
            const float p = (t + 1.0f) * 7.5f;
            const float fi = floorf(p);
            const int i0 = (int)fi;
            const float f = p - fi;
            // clamp index for the LDS read; zero the value if tap out of range
            const int i0c = min(max(i0, 0), Kc - 1);
            const int i1c = min(max(i0 + 1, 0), Kc - 1);
            float a0 = sA[i0c];
            float a1 = sA[i1c];
            a0 = ((unsigned)i0       < (unsigned)Kc) ? a0 : 0.0f;
            a1 = ((unsigned)(i0 + 1) < (unsigned)Kc) ? a1 : 0.0f;
            const float phi = a0 * (1.0f - f) + a1 * f;
            o[j] = phi + be * xx + bi;
        }
        o4[idx] = make_float4(o[0], o[1], o[2], o[3]);
    }
}

extern "C" void kernel_launch(void* const* d_in, const int* in_sizes, int n_in,
                              void* d_out, int out_size, void* d_ws, size_t ws_size,
                              hipStream_t stream) {
    const float* x     = (const float*)d_in[0];
    const float* alpha = (const float*)d_in[1];
    const float* beta  = (const float*)d_in[2];
    const float* bias  = (const float*)d_in[3];
    const float* shift = (const float*)d_in[4];
    const float* scale = (const float*)d_in[5];
    float* out = (float*)d_out;

    const int total = Bc * Cc * HW;                 // 8,388,608
    const int blocks = total / ELEMS_PER_BLOCK;     // 2048

    kan_spline_kernel<<<dim3(blocks), dim3(THREADS), 0, stream>>>(
        x, alpha, beta, bias, shift, scale, out);
}

// Round 3
// 89.428 us; speedup vs baseline: 1.0115x; 1.0115x over previous
//
#include <hip/hip_runtime.h>

// KAN 1D spline: out = phi(t) + beta*x + bias, t = clamp((x-shift)*scale, -1.5, 1.5)
// Hat basis, centers = linspace(-1,1,16), delta = 2/15 => 2-tap lerp into alpha.
//
// Optimizations vs r1:
//  - 24-entry zero-padded LDS table indexed by floor(p)+4: no per-tap range selects.
//  - bias folded into every table entry (taps' lerp weights sum to 1).
//  - pure-FMA per-element path: ~9 VALU + 2 LDS reads per element.
//  - all 4 float4 loads issued before the compute chain (explicit MLP).
//
// B=8, C=64, H=128, W=128, K=16. Memory-bound: 32 MiB in + 32 MiB out.

constexpr int Bc = 8, Cc = 64, Hc = 128, Wc = 128, Kc = 16;
constexpr int HW = Hc * Wc;                 // 16384 elements per (b,c) plane
constexpr int ELEMS_PER_BLOCK = 4096;       // quarter plane -> channel uniform per block
constexpr int THREADS = 256;
constexpr int F4_PER_THREAD = ELEMS_PER_BLOCK / 4 / THREADS;  // 4
constexpr int PAD = 4;                      // table index = floor(p) + PAD
constexpr int TBL = 24;                     // covers i0+PAD in [0,22] (+1 tap -> 23)

__global__ __launch_bounds__(THREADS)
void kan_spline_kernel(const float* __restrict__ x,
                       const float* __restrict__ alpha,
                       const float* __restrict__ beta,
                       const float* __restrict__ bias,
                       const float* __restrict__ shift,
                       const float* __restrict__ scale,
                       float* __restrict__ out)
{
    __shared__ float sA[TBL];

    const int blk = blockIdx.x;
    // 4 blocks per plane; plane index = b*Cc + c  ->  c = (blk/4) % 64
    const int c = (blk >> 2) & (Cc - 1);

    const float bi = bias[c];
    if (threadIdx.x < TBL) {
        const int ai = (int)threadIdx.x - PAD;
        const float a = ((unsigned)ai < (unsigned)Kc) ? alpha[c * Kc + ai] : 0.0f;
        sA[threadIdx.x] = a + bi;           // bias folded into table
    }
    const float sc   = scale[c];
    const float nshs = -shift[c] * sc;      // t = fma(x, sc, nshs)
    const float be   = beta[c];
    __syncthreads();

    const int base = blk * ELEMS_PER_BLOCK;
    const float4* __restrict__ x4 = reinterpret_cast<const float4*>(x + base);
    float4*       __restrict__ o4 = reinterpret_cast<float4*>(out + base);

    // Issue all loads up-front for maximal outstanding VMEM.
    float4 v[F4_PER_THREAD];
    #pragma unroll
    for (int it = 0; it < F4_PER_THREAD; ++it)
        v[it] = x4[it * THREADS + threadIdx.x];

    #pragma unroll
    for (int it = 0; it < F4_PER_THREAD; ++it) {
        float r[4] = {v[it].x, v[it].y, v[it].z, v[it].w};
        float o[4];
        #pragma unroll
        for (int j = 0; j < 4; ++j) {
            const float xx = r[j];
            float t = __builtin_fmaf(xx, sc, nshs);
            t = fminf(fmaxf(t, -1.5f), 1.5f);              // v_med3_f32
            // padded position: (t+1)*7.5 + 4  in [0.25, 22.75]
            const float pp = __builtin_fmaf(t, 7.5f, 11.5f);
            const float fi = floorf(pp);
            const float f  = pp - fi;
            const int   i0 = (int)fi;
            const float a0 = sA[i0];
            const float a1 = sA[i0 + 1];
            const float phi = __builtin_fmaf(f, a1 - a0, a0);  // includes bias
            o[j] = __builtin_fmaf(be, xx, phi);
        }
        o4[it * THREADS + threadIdx.x] = make_float4(o[0], o[1], o[2], o[3]);
    }
}

extern "C" void kernel_launch(void* const* d_in, const int* in_sizes, int n_in,
                              void* d_out, int out_size, void* d_ws, size_t ws_size,
                              hipStream_t stream) {
    const float* x     = (const float*)d_in[0];
    const float* alpha = (const float*)d_in[1];
    const float* beta  = (const float*)d_in[2];
    const float* bias  = (const float*)d_in[3];
    const float* shift = (const float*)d_in[4];
    const float* scale = (const float*)d_in[5];
    float* out = (float*)d_out;

    const int total = Bc * Cc * HW;                 // 8,388,608
    const int blocks = total / ELEMS_PER_BLOCK;     // 2048

    kan_spline_kernel<<<dim3(blocks), dim3(THREADS), 0, stream>>>(
        x, alpha, beta, bias, shift, scale, out);
}